// Round 6
// baseline (530.953 us; speedup 1.0000x reference)
//
#include <hip/hip_runtime.h>
#include <cstddef>
#include <cstdint>

constexpr int IMG = 256;
constexpr int NPIX = 65536;
constexpr int PW = 258;                 // padded dim of HWC activation buffers
constexpr size_t PREC = (size_t)PW * PW;

typedef _Float16 h8 __attribute__((ext_vector_type(8)));
typedef float f32x4 __attribute__((ext_vector_type(4)));

// ---------------------------------------------------------------------------
// Zero pad records (rows 0,257; cols 0,257) of a padded-HWC f16 buffer.
// ---------------------------------------------------------------------------
template<int CIN>
__device__ __forceinline__ void zero_pad_rec(int i, _Float16* buf)
{
  constexpr int Q = CIN / 8;
  if (i >= 1028 * Q) return;
  int pr = i / Q, qi = i - pr * Q;
  int rec;
  if (pr < 258) rec = pr;                                   // row 0
  else if (pr < 516) rec = 257 * 258 + (pr - 258);          // row 257
  else { int j = pr - 516; rec = (1 + (j >> 1)) * 258 + ((j & 1) ? 257 : 0); }
  *reinterpret_cast<uint4*>(&buf[(size_t)rec * CIN + qi * 8]) = uint4{0, 0, 0, 0};
}

template<int CIN>
__global__ __launch_bounds__(256) void zeropad_k(_Float16* __restrict__ buf)
{
  zero_pad_rec<CIN>(blockIdx.x * 256 + threadIdx.x, buf);
}

// ---------------------------------------------------------------------------
// fp32 CHW -> padded-HWC f16 (interior), pad-zeroing folded into extra blocks.
// Fused over branches via blockIdx.z.
// ---------------------------------------------------------------------------
template<int CIN>
__global__ __launch_bounds__(256) void prep_hwc_k(
    const float* __restrict__ in0, const float* __restrict__ in1,
    _Float16* __restrict__ out0, _Float16* __restrict__ out1)
{
  const int z = blockIdx.z;
  const float* in = z ? in1 : in0;
  _Float16* out = z ? out1 : out0;
  int b = blockIdx.x;
  if (b >= 256) { zero_pad_rec<CIN>((b - 256) * 256 + threadIdx.x, out); return; }
  int pix = b * 256 + threadIdx.x;
  int py = pix >> 8, px = pix & 255;
  size_t rec = ((size_t)(py + 1) * PW + px + 1) * CIN;
#pragma unroll
  for (int c0 = 0; c0 < CIN; c0 += 8) {
    _Float16 t[8];
#pragma unroll
    for (int j = 0; j < 8; ++j)
      t[j] = (_Float16)in[(size_t)(c0 + j) * NPIX + pix];
    *reinterpret_cast<uint4*>(&out[rec + c0]) = *reinterpret_cast<uint4*>(t);
  }
}

// ---------------------------------------------------------------------------
// Weight fragment slicing (hi + optional f16 residual lo):
// dst idx = ((t*KC + c)*NBF + fg)*64 + lane, 8 f16; lane holds B[k][n]:
// n = fg*16 + (l&15), cin = c*32 + (l>>4)*8 + j. Zero-fill n >= nvalid.
// ---------------------------------------------------------------------------
__device__ __forceinline__ void wfrag(
    const float* __restrict__ w, int cin_tot, int cin_off, int KC, int NBF,
    int nvalid, int idx, _Float16* __restrict__ oHi, _Float16* __restrict__ oLo)
{
  int l = idx & 63;
  int r = idx >> 6;
  int fg = r % NBF; r /= NBF;
  int c = r % KC;
  int t = r / KC;
  int n = fg * 16 + (l & 15);
  int cinb = c * 32 + (l >> 4) * 8;
  _Float16 vh[8], vl[8];
#pragma unroll
  for (int j = 0; j < 8; ++j) {
    float x = 0.f;
    if (n < nvalid) x = w[((size_t)n * cin_tot + cin_off + cinb + j) * 9 + t];
    vh[j] = (_Float16)x;
    vl[j] = (_Float16)(x - (float)vh[j]);
  }
  *reinterpret_cast<uint4*>(oHi + (size_t)idx * 8) = *reinterpret_cast<uint4*>(vh);
  if (oLo)
    *reinterpret_cast<uint4*>(oLo + (size_t)idx * 8) = *reinterpret_cast<uint4*>(vl);
}

// One launch per branch preps all conv weight buffers + the dcn B-fragments.
// wB layout: [pass p 0..17][coutfrag f 0..3][lane 0..63][8 f16]; value =
// dw[n,g,c,k] with t = p*4+(l>>4), g=t/9, k=t%9, c=j, n=f*16+(l&15).
// wf (full 128-cin fusion weights) prepped only when wf != nullptr.
// ---------------------------------------------------------------------------
__global__ __launch_bounds__(256) void wprep_all_k(
    const float* __restrict__ w0, const float* __restrict__ w1,
    const float* __restrict__ w2, const float* __restrict__ w3,
    const float* __restrict__ wf, const float* __restrict__ dw,
    _Float16* b0h, _Float16* b0l, _Float16* b1h, _Float16* b1l,
    _Float16* b2h, _Float16* b2l, _Float16* b3h, _Float16* b3l,
    _Float16* bfh, _Float16* __restrict__ wB)
{
  int idx = blockIdx.x * 256 + threadIdx.x;
  if (idx < 9216)       wfrag(w0, 128, 0, 4, 4, 64, idx, b0h, b0l);
  else if (idx < 13824) wfrag(w1, 64, 0, 2, 4, 64, idx - 9216, b1h, b1l);
  else if (idx < 18432) wfrag(w2, 64, 0, 2, 4, 64, idx - 13824, b2h, b2l);
  else if (idx < 36864) wfrag(w3, 64, 0, 2, 16, 216, idx - 18432, b3h, b3l);
  else if (idx < 41472) {
    int i = idx - 36864;
    int l = i & 63;
    int r = i >> 6;          // 0..71
    int f = r & 3;
    int p = r >> 2;          // 0..17
    int t = p * 4 + (l >> 4);
    int g = (t * 57) >> 9;   // t/9 for t<72
    int k = t - 9 * g;
    int n = f * 16 + (l & 15);
    _Float16 v[8];
#pragma unroll
    for (int j = 0; j < 8; ++j)
      v[j] = (_Float16)dw[(size_t)n * 576 + g * 72 + j * 9 + k];
    *reinterpret_cast<uint4*>(wB + (size_t)i * 8) = *reinterpret_cast<uint4*>(v);
  }
  else if (wf && idx < 50688)
    wfrag(wf, 128, 0, 4, 4, 64, idx - 41472, bfh, nullptr);
}

// ---------------------------------------------------------------------------
// MFMA implicit-GEMM 3x3 conv over padded-HWC f16, branch-fused (blockIdx.z
// selects pointer set). Block: 256 thr = 4 waves; 64 px x 64 couts; wave =
// 64px(mf4) x 16cout. A staged once in LDS (3 rows x 66 recs, 16B-slot
// rotation); B in registers (tap-lookahead global loads, L2-hot).
// XCD row-band swizzle on blockIdx.x.
// EPI 0: padded-HWC f16 out + bias + lrelu
// EPI 1: OT CHW out + bias (LDS transpose)
// ---------------------------------------------------------------------------
template<int CIN, int EPI, bool DBL, typename OT>
__global__ __launch_bounds__(256) void conv_mfma_k(
    const _Float16* __restrict__ act0, const _Float16* __restrict__ act1,
    const _Float16* __restrict__ wHi0, const _Float16* __restrict__ wHi1,
    const _Float16* __restrict__ wLo0, const _Float16* __restrict__ wLo1,
    const float* __restrict__ bias0, const float* __restrict__ bias1,
    OT* __restrict__ out0, OT* __restrict__ out1, int ncout, int NBF)
{
  constexpr int Q = CIN / 8;
  constexpr int KC = CIN / 32;
  constexpr int NT = DBL ? 2 : 1;
  constexpr int NREC = 198;            // 3 rows x 66 cols
  __shared__ __align__(16) _Float16 sA[NREC * CIN];

  const int z = blockIdx.z;
  const _Float16* __restrict__ act = z ? act1 : act0;
  const _Float16* __restrict__ wHi = z ? wHi1 : wHi0;
  const _Float16* __restrict__ wLo = z ? wLo1 : wLo0;
  const float* __restrict__ bias = z ? bias1 : bias0;
  OT* __restrict__ out = z ? out1 : out0;

  const int tid = threadIdx.x;
  const int lane = tid & 63;
  const int wv = tid >> 6;             // 0..3: cout quarter
  const int b = blockIdx.x;
  const int inner = b >> 3;
  const int y = (b & 7) * 32 + (inner & 31);   // XCD row band
  const int x0 = (inner >> 5) << 6;
  const int n0 = blockIdx.y << 6;

  // ---- stage A (rows y..y+2 padded, cols x0..x0+65), 16B-slot rotation
  for (int i = tid; i < NREC * Q; i += 256) {
    int rec = i / Q, q = i - rec * Q;
    int seg = rec / 66, xr = rec - seg * 66;
    size_t g = ((size_t)(y + seg) * PW + x0 + xr) * CIN + q * 8;
    int slot = (q + rec) & (Q - 1);
    *reinterpret_cast<uint4*>(&sA[rec * CIN + slot * 8]) =
        *reinterpret_cast<const uint4*>(&act[g]);
  }

  // ---- B register prefetch: wave covers couts n0 + wv*16 .. +15 (1 frag)
  const int fgb = (n0 >> 4) + wv;
  auto bload = [&](int t, int c, const _Float16* src) {
    return *reinterpret_cast<const h8*>(
        &src[((((size_t)t * KC + c) * NBF + fgb) * 64 + lane) * 8]);
  };
  h8 Bn[KC][NT];
#pragma unroll
  for (int c = 0; c < KC; ++c) {
    Bn[c][0] = bload(0, c, wHi);
    if (DBL) Bn[c][1] = bload(0, c, wLo);
  }

  f32x4 acc[4];
#pragma unroll
  for (int a = 0; a < 4; ++a) acc[a] = f32x4{0.f, 0.f, 0.f, 0.f};
  __syncthreads();

  const int m = lane & 15, kq = lane >> 4;
#pragma unroll 1
  for (int t = 0; t < 9; ++t) {
    h8 Bc[KC][NT];
#pragma unroll
    for (int c = 0; c < KC; ++c) {
      Bc[c][0] = Bn[c][0];
      if (DBL) Bc[c][1] = Bn[c][1];
    }
    if (t < 8) {
#pragma unroll
      for (int c = 0; c < KC; ++c) {
        Bn[c][0] = bload(t + 1, c, wHi);
        if (DBL) Bn[c][1] = bload(t + 1, c, wLo);
      }
    }
    const int lrb = (t / 3) * 66 + (t % 3) + m;
#pragma unroll
    for (int c = 0; c < KC; ++c) {
      const int q = c * 4 + kq;
#pragma unroll
      for (int mf = 0; mf < 4; ++mf) {
        int lr = lrb + mf * 16;
        int slot = (q + lr) & (Q - 1);
        h8 ah = *reinterpret_cast<const h8*>(&sA[lr * CIN + slot * 8]);
        acc[mf] = __builtin_amdgcn_mfma_f32_16x16x32_f16(
            ah, Bc[c][0], acc[mf], 0, 0, 0);
        if (DBL)
          acc[mf] = __builtin_amdgcn_mfma_f32_16x16x32_f16(
              ah, Bc[c][1], acc[mf], 0, 0, 0);
      }
    }
  }

  if (EPI == 0) {
    const int ch = wv * 16 + m;
    const float bv = bias[ch];
#pragma unroll
    for (int mf = 0; mf < 4; ++mf)
#pragma unroll
      for (int r = 0; r < 4; ++r) {
        int p = mf * 16 + kq * 4 + r;
        float v = acc[mf][r] + bv;
        v = (v >= 0.f) ? v : 0.1f * v;
        reinterpret_cast<_Float16*>(out)[((size_t)(y + 1) * PW + x0 + p + 1) * 64 + ch] =
            (_Float16)v;
      }
  } else {
    __syncthreads();                   // all waves done reading sA
    float* sF = reinterpret_cast<float*>(sA);   // [64 couts][68] scratch
    const int nl = wv * 16 + m;                  // cout 0..63
#pragma unroll
    for (int mf = 0; mf < 4; ++mf) {
      int ml = mf * 16 + kq * 4;                 // px 0..63 (4 at a time)
      f32x4 v = acc[mf];
      float bv = (n0 + nl < ncout) ? bias[n0 + nl] : 0.f;
      v[0] += bv; v[1] += bv; v[2] += bv; v[3] += bv;
      *reinterpret_cast<f32x4*>(&sF[nl * 68 + ml]) = v;
    }
    __syncthreads();
    for (int i = tid; i < 1024; i += 256) {
      int row = i >> 4, cx = (i & 15) * 4;
      int gc = n0 + row;
      if (gc < ncout) {
        f32x4 v = *reinterpret_cast<f32x4*>(&sF[row * 68 + cx]);
        size_t ob = (size_t)gc * NPIX + (size_t)y * IMG + x0 + cx;
        if (sizeof(OT) == 2) {
          _Float16 t4[4] = {(_Float16)v[0], (_Float16)v[1],
                            (_Float16)v[2], (_Float16)v[3]};
          *reinterpret_cast<uint2*>(reinterpret_cast<_Float16*>(out) + ob) =
              *reinterpret_cast<uint2*>(t4);
        } else {
          *reinterpret_cast<f32x4*>(reinterpret_cast<float*>(out) + ob) = v;
        }
      }
    }
  }
}

// ---------------------------------------------------------------------------
// feat fp32 CHW -> f16 per-group records featG[g][pix][8]; branch-fused.
// ---------------------------------------------------------------------------
__global__ __launch_bounds__(256) void featg_k(
    const float* __restrict__ in0, const float* __restrict__ in1,
    _Float16* __restrict__ out0, _Float16* __restrict__ out1)
{
  const int z = blockIdx.z;
  const float* in = z ? in1 : in0;
  _Float16* out = z ? out1 : out0;
  int pix = blockIdx.x * 256 + threadIdx.x;
#pragma unroll
  for (int g = 0; g < 8; ++g) {
    _Float16 t[8];
#pragma unroll
    for (int c = 0; c < 8; ++c)
      t[c] = (_Float16)in[(size_t)(g * 8 + c) * NPIX + pix];
    *reinterpret_cast<uint4*>(&out[((size_t)g * NPIX + pix) * 8]) =
        *reinterpret_cast<uint4*>(t);
  }
}

// ---------------------------------------------------------------------------
// MDCN sample + MFMA einsum, branch-fused (blockIdx.z). Wave = 16 px x 64
// couts; lane (m, tq) samples pixel m's bilinear vector s[8] for (g,tap)
// t = p*4+tq; s[8] IS the mfma A-fragment; 18 passes of K=32 cover K=576.
// Unroll-by-2 ping-pong pipeline (sets A/B): raws, gathers and weight frags
// all 1 pass ahead. VALU-lean addressing:
//  - raw channels linear in t (a0=2t, a1=2t+1, a2=144+t) -> monotonic 32-bit
//    byte offsets advanced by two v_adds per pass
//  - gathers/bf: 32-bit voffset off uniform base (saddr-form loads)
//  - bilinear combine in packed f16 (h8 vector ops -> v_pk_fma_f16)
// __launch_bounds__(256, 8): declare 8 waves/EU (VGPR <= 64) — residency
// experiment; prior rounds' (256,4) may have clamped waves/EU at 4.
// Branch z writes channels z*64..z*64+63 of the shared 128-ch padded actF.
// Grid (1024, 1, 2) x 4 waves = 8192 waves = full machine.
// ---------------------------------------------------------------------------
struct GS {
  h8 a, b, c, d;                       // gather corners
  _Float16 w00, w01, w10, w11;         // bilinear*mask weights (f16)
  float r0, r1, r2;                    // raw offsets/mask logits
  h8 bf0, bf1, bf2, bf3;               // weight B-fragments
};

__global__ __launch_bounds__(256, 8) void mdcn_mfma_k(
    const _Float16* __restrict__ featG0, const _Float16* __restrict__ featG1,
    const _Float16* __restrict__ o2160, const _Float16* __restrict__ o2161,
    const float* __restrict__ flow0, const float* __restrict__ flow1,
    const _Float16* __restrict__ wB0, const _Float16* __restrict__ wB1,
    const float* __restrict__ bias0, const float* __restrict__ bias1,
    _Float16* __restrict__ actF)
{
  const int z = blockIdx.z;
  const char* __restrict__ featGc =
      reinterpret_cast<const char*>(z ? featG1 : featG0);
  const char* __restrict__ o216c =
      reinterpret_cast<const char*>(z ? o2161 : o2160);
  const float* __restrict__ flow = z ? flow1 : flow0;
  const char* __restrict__ wBc = reinterpret_cast<const char*>(z ? wB1 : wB0);
  const float* __restrict__ bias = z ? bias1 : bias0;
  const int zoff = z << 6;

  const int tid = threadIdx.x;
  const int lane = tid & 63;
  const int wv = tid >> 6;
  const int b = blockIdx.x;
  const int inner = b >> 3;
  const int row = (b & 7) * 32 + (inner & 31);   // XCD row band
  const int xseg = inner >> 5;                   // 0..3
  const int m = lane & 15;
  const int tq = lane >> 4;                      // tap-slot 0..3
  const int xw = xseg * 64 + wv * 16;            // wave's base column
  const int x = xw + m;
  const int pix = row * 256 + x;

  const float fy = flow[NPIX + pix];   // flow[:, ::-1]: y-offset += flow[1]
  const float fx = flow[pix];
  const float rowf = (float)row, xf = (float)x;

  f32x4 acc[4];
#pragma unroll
  for (int f = 0; f < 4; ++f) acc[f] = f32x4{0.f, 0.f, 0.f, 0.f};

  // raw byte offsets, monotonic in pass (t = 4p + tq):
  // a0 ch = 2t, a1 ch = 2t+1, a2 ch = 144+t
  uint32_t ro0 = ((uint32_t)(2 * tq) * NPIX + (uint32_t)pix) * 2;
  uint32_t ro2 = ((uint32_t)(144 + tq) * NPIX + (uint32_t)pix) * 2;
  auto rawloadv = [&](float& a0, float& a1, float& a2) {
    a0 = (float)*reinterpret_cast<const _Float16*>(o216c + ro0);
    a1 = (float)*reinterpret_cast<const _Float16*>(o216c + ro0 + NPIX * 2);
    a2 = (float)*reinterpret_cast<const _Float16*>(o216c + ro2);
    ro0 += 8u * NPIX * 2;            // t += 4 -> 2t += 8 channels
    ro2 += 4u * NPIX * 2;
  };

  // params + issue gathers for pass p into set o (fast tanh/sigmoid)
  auto setup = [&](int p, float s0, float s1, float s2, GS& o) {
    const int t = p * 4 + tq;
    const int g = (t * 57) >> 9;                 // t/9 for t<72
    const int k = t - 9 * g;
    const int kd = (k * 11) >> 5;                // k/3
    const int km = k - 3 * kd;                   // k%3
    const float mm = __builtin_amdgcn_rcpf(1.f + __expf(-s2));
    const float e0 = __expf(2.f * s0);
    const float e1 = __expf(2.f * s1);
    const float th0 = 1.f - 2.f * __builtin_amdgcn_rcpf(e0 + 1.f);
    const float th1 = 1.f - 2.f * __builtin_amdgcn_rcpf(e1 + 1.f);
    const float pyf = rowf + (float)(kd - 1) + 10.f * th0 + fy;
    const float pxf = xf + (float)(km - 1) + 10.f * th1 + fx;
    const float y0f = floorf(pyf), x0f = floorf(pxf);
    const float ly = pyf - y0f, lx = pxf - x0f;
    const int y0 = (int)y0f, x0i = (int)x0f;
    const int y1 = y0 + 1, x1 = x0i + 1;
    const bool vy0 = (unsigned)y0 < (unsigned)IMG, vy1 = (unsigned)y1 < (unsigned)IMG;
    const bool vx0 = (unsigned)x0i < (unsigned)IMG, vx1 = (unsigned)x1 < (unsigned)IMG;
    const int y0c = min(max(y0, 0), IMG - 1), y1c = min(max(y1, 0), IMG - 1);
    const int x0c = min(max(x0i, 0), IMG - 1), x1c = min(max(x1, 0), IMG - 1);
    const float oy = 1.f - ly, ox = 1.f - lx;
    const float py0 = oy * mm, py1 = ly * mm;
    const float w00 = (vy0 && vx0) ? py0 * ox : 0.f;
    const float w01 = (vy0 && vx1) ? py0 * lx : 0.f;
    const float w10 = (vy1 && vx0) ? py1 * ox : 0.f;
    const float w11 = (vy1 && vx1) ? py1 * lx : 0.f;
    o.w00 = (_Float16)w00; o.w01 = (_Float16)w01;
    o.w10 = (_Float16)w10; o.w11 = (_Float16)w11;
    // 32-bit byte offsets into featG[g][pix][8] (16 B/record)
    const uint32_t gb = ((uint32_t)g << 16);
    const uint32_t ry0 = gb + ((uint32_t)y0c << 8);
    const uint32_t ry1 = gb + ((uint32_t)y1c << 8);
    o.a = *reinterpret_cast<const h8*>(featGc + ((ry0 + x0c) << 4));
    o.b = *reinterpret_cast<const h8*>(featGc + ((ry0 + x1c) << 4));
    o.c = *reinterpret_cast<const h8*>(featGc + ((ry1 + x0c) << 4));
    o.d = *reinterpret_cast<const h8*>(featGc + ((ry1 + x1c) << 4));
  };

  const uint32_t lane16 = (uint32_t)lane * 16;
  auto bfload = [&](int p, GS& o) {
    const uint32_t w = (uint32_t)p * 4096 + lane16;
    o.bf0 = *reinterpret_cast<const h8*>(wBc + w);
    o.bf1 = *reinterpret_cast<const h8*>(wBc + w + 1024);
    o.bf2 = *reinterpret_cast<const h8*>(wBc + w + 2048);
    o.bf3 = *reinterpret_cast<const h8*>(wBc + w + 3072);
  };

  auto consume = [&](GS& cur) {
    h8 af = cur.a * cur.w00 + cur.b * cur.w01 +
            cur.c * cur.w10 + cur.d * cur.w11;   // packed f16 fma
    acc[0] = __builtin_amdgcn_mfma_f32_16x16x32_f16(af, cur.bf0, acc[0], 0, 0, 0);
    acc[1] = __builtin_amdgcn_mfma_f32_16x16x32_f16(af, cur.bf1, acc[1], 0, 0, 0);
    acc[2] = __builtin_amdgcn_mfma_f32_16x16x32_f16(af, cur.bf2, acc[2], 0, 0, 0);
    acc[3] = __builtin_amdgcn_mfma_f32_16x16x32_f16(af, cur.bf3, acc[3], 0, 0, 0);
  };

  auto body = [&](int p, GS& cur, GS& nxt) {
    setup(p + 1, nxt.r0, nxt.r1, nxt.r2, nxt);   // gathers for p+1
    rawloadv(cur.r0, cur.r1, cur.r2);            // raws for p+2 (monotonic)
    bfload(p + 1, nxt);                          // weight frags for p+1
    consume(cur);
  };

  GS A, B;
  // prologue: fill pass-0 state and pass-1 raws (rawloadv calls are ordered
  // p = 0, 1, then 2..17 inside the bodies — offsets advance monotonically)
  {
    float t0, t1, t2;
    rawloadv(t0, t1, t2);                        // p = 0
    rawloadv(B.r0, B.r1, B.r2);                  // p = 1
    bfload(0, A);
    setup(0, t0, t1, t2, A);
  }

#pragma unroll 1
  for (int it = 0; it < 8; ++it) {     // bodies p = 0..15 (full pipeline)
    body(2 * it, A, B);
    body(2 * it + 1, B, A);
  }
  // tail: p=16 (no rawload), p=17 (consume only)
  setup(17, B.r0, B.r1, B.r2, B);
  bfload(17, B);
  consume(A);
  consume(B);

  // epilogue: D[pixel = tq*4+r][cout = f*16+m] -> 128-ch padded-HWC + bias
  const size_t rb = ((size_t)(row + 1) * PW + xw + 1) * 128 + zoff;
#pragma unroll
  for (int f = 0; f < 4; ++f) {
    const int ch = f * 16 + m;
    const float bv = bias[ch];
#pragma unroll
    for (int r = 0; r < 4; ++r)
      actF[rb + (size_t)(tq * 4 + r) * 128 + ch] = (_Float16)(acc[f][r] + bv);
  }
}

// ---------------------------------------------------------------------------
extern "C" void kernel_launch(void* const* d_in, const int* in_sizes, int n_in,
                              void* d_out, int out_size, void* d_ws, size_t ws_size,
                              hipStream_t stream)
{
  const float* feat[2]  = {(const float*)d_in[0], (const float*)d_in[1]};
  const float* extra[2] = {(const float*)d_in[2], (const float*)d_in[3]};
  const float* flow[2]  = {(const float*)d_in[4], (const float*)d_in[5]};
  const float* ow[2][4];
  const float* ob[2][4];
  for (int br = 0; br < 2; ++br)
    for (int j = 0; j < 4; ++j) {
      ow[br][j] = (const float*)d_in[6 + br * 8 + j * 2];
      ob[br][j] = (const float*)d_in[6 + br * 8 + j * 2 + 1];
    }
  const float* dcnw[2] = {(const float*)d_in[22], (const float*)d_in[24]};
  const float* dcnb[2] = {(const float*)d_in[23], (const float*)d_in[25]};
  const float* fusw = (const float*)d_in[26];
  const float* fusb = (const float*)d_in[27];

  char* wsb = (char*)d_ws;
  size_t off = 0;
  auto alloc = [&](size_t bytes) {
    void* p = wsb + off;
    off += (bytes + 255) & ~(size_t)255;
    return p;
  };
  // R1 (34.1 MB), liveness-aliased: actI0/1 (conv0 input) -> actB0/1
  // (conv1 out / conv2 in) -> actF 128-ch (mdcn out / fusion in).
  _Float16* R1 = (_Float16*)alloc(PREC * 128 * 2 * 2);
  _Float16* actI0 = R1;
  _Float16* actI1 = R1 + PREC * 128;
  _Float16* actB0 = R1;
  _Float16* actB1 = R1 + PREC * 64;
  _Float16* actF  = R1;                 // 128-ch padded-HWC
  // R2: actA0/1; after conv3, featG0/1 alias the same space.
  _Float16* R2 = (_Float16*)alloc(PREC * 64 * 2 * 2);
  _Float16* actA0 = R2;
  _Float16* actA1 = R2 + PREC * 64;
  _Float16* featG0 = R2;
  _Float16* featG1 = R2 + PREC * 64;
  _Float16* o2160 = (_Float16*)alloc((size_t)216 * NPIX * 2 * 2);
  _Float16* o2161 = o2160 + (size_t)216 * NPIX;
  _Float16* wB0 = (_Float16*)alloc(73728 * 2);
  _Float16* wB1 = wB0 + 36864;
  _Float16* wb0h[2] = {(_Float16*)alloc(147456), (_Float16*)alloc(147456)};
  _Float16* wb0l[2] = {(_Float16*)alloc(147456), (_Float16*)alloc(147456)};
  _Float16* wb1h[2] = {(_Float16*)alloc(73728), (_Float16*)alloc(73728)};
  _Float16* wb1l[2] = {(_Float16*)alloc(73728), (_Float16*)alloc(73728)};
  _Float16* wb2h[2] = {(_Float16*)alloc(73728), (_Float16*)alloc(73728)};
  _Float16* wb2l[2] = {(_Float16*)alloc(73728), (_Float16*)alloc(73728)};
  _Float16* wb3h[2] = {(_Float16*)alloc(294912), (_Float16*)alloc(294912)};
  _Float16* wb3l[2] = {(_Float16*)alloc(294912), (_Float16*)alloc(294912)};
  _Float16* wbFh = (_Float16*)alloc(147456);   // full 128-cin fusion weights
  float* outp = (float*)d_out;

  dim3 blk256(256);
  zeropad_k<64><<<dim3(33), blk256, 0, stream>>>(actA0);
  zeropad_k<64><<<dim3(33), blk256, 0, stream>>>(actA1);

  // weight prep (both branches; br0 also preps full fusion weights)
  wprep_all_k<<<dim3(198), blk256, 0, stream>>>(
      ow[0][0], ow[0][1], ow[0][2], ow[0][3], fusw, dcnw[0],
      wb0h[0], wb0l[0], wb1h[0], wb1l[0], wb2h[0], wb2l[0],
      wb3h[0], wb3l[0], wbFh, wB0);
  wprep_all_k<<<dim3(162), blk256, 0, stream>>>(
      ow[1][0], ow[1][1], ow[1][2], ow[1][3], nullptr, dcnw[1],
      wb0h[1], wb0l[1], wb1h[1], wb1l[1], wb2h[1], wb2l[1],
      wb3h[1], wb3l[1], nullptr, wB1);

  // activations prep, both branches fused
  prep_hwc_k<128><<<dim3(321, 1, 2), blk256, 0, stream>>>(
      extra[0], extra[1], actI0, actI1);

  // offset network, branch-fused (f16 MFMA, hi/lo-split weights)
  conv_mfma_k<128, 0, true, _Float16><<<dim3(1024, 1, 2), blk256, 0, stream>>>(
      actI0, actI1, wb0h[0], wb0h[1], wb0l[0], wb0l[1],
      ob[0][0], ob[1][0], actA0, actA1, 64, 4);
  zeropad_k<64><<<dim3(33), blk256, 0, stream>>>(actB0);  // actI dead
  zeropad_k<64><<<dim3(33), blk256, 0, stream>>>(actB1);
  conv_mfma_k<64, 0, true, _Float16><<<dim3(1024, 1, 2), blk256, 0, stream>>>(
      actA0, actA1, wb1h[0], wb1h[1], wb1l[0], wb1l[1],
      ob[0][1], ob[1][1], actB0, actB1, 64, 4);
  conv_mfma_k<64, 0, true, _Float16><<<dim3(1024, 1, 2), blk256, 0, stream>>>(
      actB0, actB1, wb2h[0], wb2h[1], wb2l[0], wb2l[1],
      ob[0][2], ob[1][2], actA0, actA1, 64, 4);
  zeropad_k<128><<<dim3(65), blk256, 0, stream>>>(actF);  // actB dead
  conv_mfma_k<64, 1, true, _Float16><<<dim3(1024, 4, 2), blk256, 0, stream>>>(
      actA0, actA1, wb3h[0], wb3h[1], wb3l[0], wb3l[1],
      ob[0][3], ob[1][3], o2160, o2161, 216, 16);

  // deformable conv: featG aliases actA (dead after conv3)
  featg_k<<<dim3(256, 1, 2), blk256, 0, stream>>>(
      feat[0], feat[1], featG0, featG1);
  mdcn_mfma_k<<<dim3(1024, 1, 2), blk256, 0, stream>>>(
      featG0, featG1, o2160, o2161, flow[0], flow[1],
      wB0, wB1, dcnb[0], dcnb[1], actF);

  // single fusion conv over the 128-ch actF
  conv_mfma_k<128, 1, false, float><<<dim3(1024, 1, 1), blk256, 0, stream>>>(
      actF, actF, wbFh, wbFh, nullptr, nullptr,
      fusb, fusb, outp, outp, 64, 4);
}

// Round 7
// 488.357 us; speedup vs baseline: 1.0872x; 1.0872x over previous
//
#include <hip/hip_runtime.h>
#include <cstddef>
#include <cstdint>

constexpr int IMG = 256;
constexpr int NPIX = 65536;
constexpr int PW = 258;                 // padded dim of HWC activation buffers
constexpr size_t PREC = (size_t)PW * PW;

typedef _Float16 h8 __attribute__((ext_vector_type(8)));
typedef float f32x4 __attribute__((ext_vector_type(4)));

// ---------------------------------------------------------------------------
// Zero pad records (rows 0,257; cols 0,257) of a padded-HWC f16 buffer.
// ---------------------------------------------------------------------------
template<int CIN>
__device__ __forceinline__ void zero_pad_rec(int i, _Float16* buf)
{
  constexpr int Q = CIN / 8;
  if (i >= 1028 * Q) return;
  int pr = i / Q, qi = i - pr * Q;
  int rec;
  if (pr < 258) rec = pr;                                   // row 0
  else if (pr < 516) rec = 257 * 258 + (pr - 258);          // row 257
  else { int j = pr - 516; rec = (1 + (j >> 1)) * 258 + ((j & 1) ? 257 : 0); }
  *reinterpret_cast<uint4*>(&buf[(size_t)rec * CIN + qi * 8]) = uint4{0, 0, 0, 0};
}

template<int CIN>
__global__ __launch_bounds__(256) void zeropad_k(_Float16* __restrict__ buf)
{
  zero_pad_rec<CIN>(blockIdx.x * 256 + threadIdx.x, buf);
}

// ---------------------------------------------------------------------------
// fp32 CHW -> padded-HWC f16 (interior), pad-zeroing folded into extra blocks.
// Fused over branches via blockIdx.z.
// ---------------------------------------------------------------------------
template<int CIN>
__global__ __launch_bounds__(256) void prep_hwc_k(
    const float* __restrict__ in0, const float* __restrict__ in1,
    _Float16* __restrict__ out0, _Float16* __restrict__ out1)
{
  const int z = blockIdx.z;
  const float* in = z ? in1 : in0;
  _Float16* out = z ? out1 : out0;
  int b = blockIdx.x;
  if (b >= 256) { zero_pad_rec<CIN>((b - 256) * 256 + threadIdx.x, out); return; }
  int pix = b * 256 + threadIdx.x;
  int py = pix >> 8, px = pix & 255;
  size_t rec = ((size_t)(py + 1) * PW + px + 1) * CIN;
#pragma unroll
  for (int c0 = 0; c0 < CIN; c0 += 8) {
    _Float16 t[8];
#pragma unroll
    for (int j = 0; j < 8; ++j)
      t[j] = (_Float16)in[(size_t)(c0 + j) * NPIX + pix];
    *reinterpret_cast<uint4*>(&out[rec + c0]) = *reinterpret_cast<uint4*>(t);
  }
}

// ---------------------------------------------------------------------------
// Weight fragment slicing (hi + optional f16 residual lo):
// dst idx = ((t*KC + c)*NBF + fg)*64 + lane, 8 f16; lane holds B[k][n]:
// n = fg*16 + (l&15), cin = c*32 + (l>>4)*8 + j. Zero-fill n >= nvalid.
// ---------------------------------------------------------------------------
__device__ __forceinline__ void wfrag(
    const float* __restrict__ w, int cin_tot, int cin_off, int KC, int NBF,
    int nvalid, int idx, _Float16* __restrict__ oHi, _Float16* __restrict__ oLo)
{
  int l = idx & 63;
  int r = idx >> 6;
  int fg = r % NBF; r /= NBF;
  int c = r % KC;
  int t = r / KC;
  int n = fg * 16 + (l & 15);
  int cinb = c * 32 + (l >> 4) * 8;
  _Float16 vh[8], vl[8];
#pragma unroll
  for (int j = 0; j < 8; ++j) {
    float x = 0.f;
    if (n < nvalid) x = w[((size_t)n * cin_tot + cin_off + cinb + j) * 9 + t];
    vh[j] = (_Float16)x;
    vl[j] = (_Float16)(x - (float)vh[j]);
  }
  *reinterpret_cast<uint4*>(oHi + (size_t)idx * 8) = *reinterpret_cast<uint4*>(vh);
  if (oLo)
    *reinterpret_cast<uint4*>(oLo + (size_t)idx * 8) = *reinterpret_cast<uint4*>(vl);
}

// One launch per branch preps all conv weight buffers + the dcn B-fragments.
// wB layout: [pass p 0..17][coutfrag f 0..3][lane 0..63][8 f16]; value =
// dw[n,g,c,k] with t = p*4+(l>>4), g=t/9, k=t%9, c=j, n=f*16+(l&15).
// wf (full 128-cin fusion weights) prepped only when wf != nullptr.
// ---------------------------------------------------------------------------
__global__ __launch_bounds__(256) void wprep_all_k(
    const float* __restrict__ w0, const float* __restrict__ w1,
    const float* __restrict__ w2, const float* __restrict__ w3,
    const float* __restrict__ wf, const float* __restrict__ dw,
    _Float16* b0h, _Float16* b0l, _Float16* b1h, _Float16* b1l,
    _Float16* b2h, _Float16* b2l, _Float16* b3h, _Float16* b3l,
    _Float16* bfh, _Float16* __restrict__ wB)
{
  int idx = blockIdx.x * 256 + threadIdx.x;
  if (idx < 9216)       wfrag(w0, 128, 0, 4, 4, 64, idx, b0h, b0l);
  else if (idx < 13824) wfrag(w1, 64, 0, 2, 4, 64, idx - 9216, b1h, b1l);
  else if (idx < 18432) wfrag(w2, 64, 0, 2, 4, 64, idx - 13824, b2h, b2l);
  else if (idx < 36864) wfrag(w3, 64, 0, 2, 16, 216, idx - 18432, b3h, b3l);
  else if (idx < 41472) {
    int i = idx - 36864;
    int l = i & 63;
    int r = i >> 6;          // 0..71
    int f = r & 3;
    int p = r >> 2;          // 0..17
    int t = p * 4 + (l >> 4);
    int g = (t * 57) >> 9;   // t/9 for t<72
    int k = t - 9 * g;
    int n = f * 16 + (l & 15);
    _Float16 v[8];
#pragma unroll
    for (int j = 0; j < 8; ++j)
      v[j] = (_Float16)dw[(size_t)n * 576 + g * 72 + j * 9 + k];
    *reinterpret_cast<uint4*>(wB + (size_t)i * 8) = *reinterpret_cast<uint4*>(v);
  }
  else if (wf && idx < 50688)
    wfrag(wf, 128, 0, 4, 4, 64, idx - 41472, bfh, nullptr);
}

// ---------------------------------------------------------------------------
// MFMA implicit-GEMM 3x3 conv over padded-HWC f16, branch-fused (blockIdx.z
// selects pointer set). Block: 256 thr = 4 waves; 64 px x 64 couts; wave =
// 64px(mf4) x 16cout. A staged once in LDS (3 rows x 66 recs, 16B-slot
// rotation); B in registers (tap-lookahead global loads, L2-hot).
// XCD row-band swizzle on blockIdx.x.
// EPI 0: padded-HWC f16 out + bias + lrelu
// EPI 1: OT CHW out + bias (LDS transpose)
// ---------------------------------------------------------------------------
template<int CIN, int EPI, bool DBL, typename OT>
__global__ __launch_bounds__(256) void conv_mfma_k(
    const _Float16* __restrict__ act0, const _Float16* __restrict__ act1,
    const _Float16* __restrict__ wHi0, const _Float16* __restrict__ wHi1,
    const _Float16* __restrict__ wLo0, const _Float16* __restrict__ wLo1,
    const float* __restrict__ bias0, const float* __restrict__ bias1,
    OT* __restrict__ out0, OT* __restrict__ out1, int ncout, int NBF)
{
  constexpr int Q = CIN / 8;
  constexpr int KC = CIN / 32;
  constexpr int NT = DBL ? 2 : 1;
  constexpr int NREC = 198;            // 3 rows x 66 cols
  __shared__ __align__(16) _Float16 sA[NREC * CIN];

  const int z = blockIdx.z;
  const _Float16* __restrict__ act = z ? act1 : act0;
  const _Float16* __restrict__ wHi = z ? wHi1 : wHi0;
  const _Float16* __restrict__ wLo = z ? wLo1 : wLo0;
  const float* __restrict__ bias = z ? bias1 : bias0;
  OT* __restrict__ out = z ? out1 : out0;

  const int tid = threadIdx.x;
  const int lane = tid & 63;
  const int wv = tid >> 6;             // 0..3: cout quarter
  const int b = blockIdx.x;
  const int inner = b >> 3;
  const int y = (b & 7) * 32 + (inner & 31);   // XCD row band
  const int x0 = (inner >> 5) << 6;
  const int n0 = blockIdx.y << 6;

  // ---- stage A (rows y..y+2 padded, cols x0..x0+65), 16B-slot rotation
  for (int i = tid; i < NREC * Q; i += 256) {
    int rec = i / Q, q = i - rec * Q;
    int seg = rec / 66, xr = rec - seg * 66;
    size_t g = ((size_t)(y + seg) * PW + x0 + xr) * CIN + q * 8;
    int slot = (q + rec) & (Q - 1);
    *reinterpret_cast<uint4*>(&sA[rec * CIN + slot * 8]) =
        *reinterpret_cast<const uint4*>(&act[g]);
  }

  // ---- B register prefetch: wave covers couts n0 + wv*16 .. +15 (1 frag)
  const int fgb = (n0 >> 4) + wv;
  auto bload = [&](int t, int c, const _Float16* src) {
    return *reinterpret_cast<const h8*>(
        &src[((((size_t)t * KC + c) * NBF + fgb) * 64 + lane) * 8]);
  };
  h8 Bn[KC][NT];
#pragma unroll
  for (int c = 0; c < KC; ++c) {
    Bn[c][0] = bload(0, c, wHi);
    if (DBL) Bn[c][1] = bload(0, c, wLo);
  }

  f32x4 acc[4];
#pragma unroll
  for (int a = 0; a < 4; ++a) acc[a] = f32x4{0.f, 0.f, 0.f, 0.f};
  __syncthreads();

  const int m = lane & 15, kq = lane >> 4;
#pragma unroll 1
  for (int t = 0; t < 9; ++t) {
    h8 Bc[KC][NT];
#pragma unroll
    for (int c = 0; c < KC; ++c) {
      Bc[c][0] = Bn[c][0];
      if (DBL) Bc[c][1] = Bn[c][1];
    }
    if (t < 8) {
#pragma unroll
      for (int c = 0; c < KC; ++c) {
        Bn[c][0] = bload(t + 1, c, wHi);
        if (DBL) Bn[c][1] = bload(t + 1, c, wLo);
      }
    }
    const int lrb = (t / 3) * 66 + (t % 3) + m;
#pragma unroll
    for (int c = 0; c < KC; ++c) {
      const int q = c * 4 + kq;
#pragma unroll
      for (int mf = 0; mf < 4; ++mf) {
        int lr = lrb + mf * 16;
        int slot = (q + lr) & (Q - 1);
        h8 ah = *reinterpret_cast<const h8*>(&sA[lr * CIN + slot * 8]);
        acc[mf] = __builtin_amdgcn_mfma_f32_16x16x32_f16(
            ah, Bc[c][0], acc[mf], 0, 0, 0);
        if (DBL)
          acc[mf] = __builtin_amdgcn_mfma_f32_16x16x32_f16(
              ah, Bc[c][1], acc[mf], 0, 0, 0);
      }
    }
  }

  if (EPI == 0) {
    const int ch = wv * 16 + m;
    const float bv = bias[ch];
#pragma unroll
    for (int mf = 0; mf < 4; ++mf)
#pragma unroll
      for (int r = 0; r < 4; ++r) {
        int p = mf * 16 + kq * 4 + r;
        float v = acc[mf][r] + bv;
        v = (v >= 0.f) ? v : 0.1f * v;
        reinterpret_cast<_Float16*>(out)[((size_t)(y + 1) * PW + x0 + p + 1) * 64 + ch] =
            (_Float16)v;
      }
  } else {
    __syncthreads();                   // all waves done reading sA
    float* sF = reinterpret_cast<float*>(sA);   // [64 couts][68] scratch
    const int nl = wv * 16 + m;                  // cout 0..63
#pragma unroll
    for (int mf = 0; mf < 4; ++mf) {
      int ml = mf * 16 + kq * 4;                 // px 0..63 (4 at a time)
      f32x4 v = acc[mf];
      float bv = (n0 + nl < ncout) ? bias[n0 + nl] : 0.f;
      v[0] += bv; v[1] += bv; v[2] += bv; v[3] += bv;
      *reinterpret_cast<f32x4*>(&sF[nl * 68 + ml]) = v;
    }
    __syncthreads();
    for (int i = tid; i < 1024; i += 256) {
      int row = i >> 4, cx = (i & 15) * 4;
      int gc = n0 + row;
      if (gc < ncout) {
        f32x4 v = *reinterpret_cast<f32x4*>(&sF[row * 68 + cx]);
        size_t ob = (size_t)gc * NPIX + (size_t)y * IMG + x0 + cx;
        if (sizeof(OT) == 2) {
          _Float16 t4[4] = {(_Float16)v[0], (_Float16)v[1],
                            (_Float16)v[2], (_Float16)v[3]};
          *reinterpret_cast<uint2*>(reinterpret_cast<_Float16*>(out) + ob) =
              *reinterpret_cast<uint2*>(t4);
        } else {
          *reinterpret_cast<f32x4*>(reinterpret_cast<float*>(out) + ob) = v;
        }
      }
    }
  }
}

// ---------------------------------------------------------------------------
// feat fp32 CHW -> f16 per-group records featG[g][pix][8]; branch-fused.
// ---------------------------------------------------------------------------
__global__ __launch_bounds__(256) void featg_k(
    const float* __restrict__ in0, const float* __restrict__ in1,
    _Float16* __restrict__ out0, _Float16* __restrict__ out1)
{
  const int z = blockIdx.z;
  const float* in = z ? in1 : in0;
  _Float16* out = z ? out1 : out0;
  int pix = blockIdx.x * 256 + threadIdx.x;
#pragma unroll
  for (int g = 0; g < 8; ++g) {
    _Float16 t[8];
#pragma unroll
    for (int c = 0; c < 8; ++c)
      t[c] = (_Float16)in[(size_t)(g * 8 + c) * NPIX + pix];
    *reinterpret_cast<uint4*>(&out[((size_t)g * NPIX + pix) * 8]) =
        *reinterpret_cast<uint4*>(t);
  }
}

// ---------------------------------------------------------------------------
// MDCN sample + MFMA einsum, branch-fused (blockIdx.z). Wave = 16 px x 64
// couts; lane (m, tq) samples pixel m's bilinear vector s[8] for (g,tap)
// t = p*4+tq; s[8] IS the mfma A-fragment; 18 passes of K=32 cover K=576.
// Unroll-by-2 ping-pong pipeline (sets A/B): raws and gathers 1 pass ahead.
// Weight B-fragments are COOPERATIVELY LDS-STAGED (TD-probe reduction):
// wave w loads only chunk f=w (1 KB) of wB[p+1] and ds_writes it; consume
// reads all 4 fragments via ds_read_b128 (LDS pipe, not TA/TD). Triple
// buffer (12 KB), one __syncthreads per pass placed to drain exactly the
// loads consume(p) is about to use (gathers keep 1 pass of overlap).
// Branch z writes channels z*64..z*64+63 of the shared 128-ch padded actF.
// Grid (1024, 1, 2) x 4 waves = 8192 waves.
// ---------------------------------------------------------------------------
struct GS {
  h8 a, b, c, d;                       // gather corners
  _Float16 w00, w01, w10, w11;         // bilinear*mask weights (f16)
  float r0, r1, r2;                    // raw offsets/mask logits
};

__global__ __launch_bounds__(256, 4) void mdcn_mfma_k(
    const _Float16* __restrict__ featG0, const _Float16* __restrict__ featG1,
    const _Float16* __restrict__ o2160, const _Float16* __restrict__ o2161,
    const float* __restrict__ flow0, const float* __restrict__ flow1,
    const _Float16* __restrict__ wB0, const _Float16* __restrict__ wB1,
    const float* __restrict__ bias0, const float* __restrict__ bias1,
    _Float16* __restrict__ actF)
{
  __shared__ __align__(16) _Float16 sWB[3 * 2048];   // 3 bufs x 4 KB

  const int z = blockIdx.z;
  const char* __restrict__ featGc =
      reinterpret_cast<const char*>(z ? featG1 : featG0);
  const char* __restrict__ o216c =
      reinterpret_cast<const char*>(z ? o2161 : o2160);
  const float* __restrict__ flow = z ? flow1 : flow0;
  const char* __restrict__ wBc = reinterpret_cast<const char*>(z ? wB1 : wB0);
  const float* __restrict__ bias = z ? bias1 : bias0;
  const int zoff = z << 6;

  const int tid = threadIdx.x;
  const int lane = tid & 63;
  const int wv = tid >> 6;
  const int b = blockIdx.x;
  const int inner = b >> 3;
  const int row = (b & 7) * 32 + (inner & 31);   // XCD row band
  const int xseg = inner >> 5;                   // 0..3
  const int m = lane & 15;
  const int tq = lane >> 4;                      // tap-slot 0..3
  const int xw = xseg * 64 + wv * 16;            // wave's base column
  const int x = xw + m;
  const int pix = row * 256 + x;

  const float fy = flow[NPIX + pix];   // flow[:, ::-1]: y-offset += flow[1]
  const float fx = flow[pix];
  const float rowf = (float)row, xf = (float)x;
  const uint32_t wvb = (uint32_t)wv << 10;       // wave's byte chunk in wB
  const uint32_t lane16 = (uint32_t)lane * 16;
  const int wvh = wv << 9;                       // wave's f16 chunk in sWB

  f32x4 acc[4];
#pragma unroll
  for (int f = 0; f < 4; ++f) acc[f] = f32x4{0.f, 0.f, 0.f, 0.f};

  // raw byte offsets, monotonic in pass (t = 4p + tq):
  // a0 ch = 2t, a1 ch = 2t+1, a2 ch = 144+t
  uint32_t ro0 = ((uint32_t)(2 * tq) * NPIX + (uint32_t)pix) * 2;
  uint32_t ro2 = ((uint32_t)(144 + tq) * NPIX + (uint32_t)pix) * 2;
  auto rawloadv = [&](float& a0, float& a1, float& a2) {
    a0 = (float)*reinterpret_cast<const _Float16*>(o216c + ro0);
    a1 = (float)*reinterpret_cast<const _Float16*>(o216c + ro0 + NPIX * 2);
    a2 = (float)*reinterpret_cast<const _Float16*>(o216c + ro2);
    ro0 += 8u * NPIX * 2;            // t += 4 -> 2t += 8 channels
    ro2 += 4u * NPIX * 2;
  };

  // params + issue gathers for pass p into set o (fast tanh/sigmoid)
  auto setup = [&](int p, float s0, float s1, float s2, GS& o) {
    const int t = p * 4 + tq;
    const int g = (t * 57) >> 9;                 // t/9 for t<72
    const int k = t - 9 * g;
    const int kd = (k * 11) >> 5;                // k/3
    const int km = k - 3 * kd;                   // k%3
    const float mm = __builtin_amdgcn_rcpf(1.f + __expf(-s2));
    const float e0 = __expf(2.f * s0);
    const float e1 = __expf(2.f * s1);
    const float th0 = 1.f - 2.f * __builtin_amdgcn_rcpf(e0 + 1.f);
    const float th1 = 1.f - 2.f * __builtin_amdgcn_rcpf(e1 + 1.f);
    const float pyf = rowf + (float)(kd - 1) + 10.f * th0 + fy;
    const float pxf = xf + (float)(km - 1) + 10.f * th1 + fx;
    const float y0f = floorf(pyf), x0f = floorf(pxf);
    const float ly = pyf - y0f, lx = pxf - x0f;
    const int y0 = (int)y0f, x0i = (int)x0f;
    const int y1 = y0 + 1, x1 = x0i + 1;
    const bool vy0 = (unsigned)y0 < (unsigned)IMG, vy1 = (unsigned)y1 < (unsigned)IMG;
    const bool vx0 = (unsigned)x0i < (unsigned)IMG, vx1 = (unsigned)x1 < (unsigned)IMG;
    const int y0c = min(max(y0, 0), IMG - 1), y1c = min(max(y1, 0), IMG - 1);
    const int x0c = min(max(x0i, 0), IMG - 1), x1c = min(max(x1, 0), IMG - 1);
    const float oy = 1.f - ly, ox = 1.f - lx;
    const float py0 = oy * mm, py1 = ly * mm;
    const float w00 = (vy0 && vx0) ? py0 * ox : 0.f;
    const float w01 = (vy0 && vx1) ? py0 * lx : 0.f;
    const float w10 = (vy1 && vx0) ? py1 * ox : 0.f;
    const float w11 = (vy1 && vx1) ? py1 * lx : 0.f;
    o.w00 = (_Float16)w00; o.w01 = (_Float16)w01;
    o.w10 = (_Float16)w10; o.w11 = (_Float16)w11;
    // 32-bit byte offsets into featG[g][pix][8] (16 B/record)
    const uint32_t gb = ((uint32_t)g << 16);
    const uint32_t ry0 = gb + ((uint32_t)y0c << 8);
    const uint32_t ry1 = gb + ((uint32_t)y1c << 8);
    o.a = *reinterpret_cast<const h8*>(featGc + ((ry0 + x0c) << 4));
    o.b = *reinterpret_cast<const h8*>(featGc + ((ry0 + x1c) << 4));
    o.c = *reinterpret_cast<const h8*>(featGc + ((ry1 + x0c) << 4));
    o.d = *reinterpret_cast<const h8*>(featGc + ((ry1 + x1c) << 4));
  };

  auto consume = [&](GS& cur, int bufi) {
    const _Float16* wp = &sWB[bufi * 2048 + lane * 8];
    h8 bf0 = *reinterpret_cast<const h8*>(wp);
    h8 bf1 = *reinterpret_cast<const h8*>(wp + 512);
    h8 bf2 = *reinterpret_cast<const h8*>(wp + 1024);
    h8 bf3 = *reinterpret_cast<const h8*>(wp + 1536);
    h8 af = cur.a * cur.w00 + cur.b * cur.w01 +
            cur.c * cur.w10 + cur.d * cur.w11;   // packed f16 fma
    acc[0] = __builtin_amdgcn_mfma_f32_16x16x32_f16(af, bf0, acc[0], 0, 0, 0);
    acc[1] = __builtin_amdgcn_mfma_f32_16x16x32_f16(af, bf1, acc[1], 0, 0, 0);
    acc[2] = __builtin_amdgcn_mfma_f32_16x16x32_f16(af, bf2, acc[2], 0, 0, 0);
    acc[3] = __builtin_amdgcn_mfma_f32_16x16x32_f16(af, bf3, acc[3], 0, 0, 0);
  };

  // body(p): stage wB(p+1) chunk f=wv -> LDS buf[(p+1)%3]; raws for p+2;
  // barrier (drains gathers(p) + stage); setup(p+1) gathers; consume(p).
  auto body = [&](int p, int bc, GS& cur, GS& nxt) {
    const int bs = (bc == 2) ? 0 : bc + 1;
    h8 tw = *reinterpret_cast<const h8*>(
        wBc + (size_t)(p + 1) * 4096 + wvb + lane16);
    rawloadv(cur.r0, cur.r1, cur.r2);
    *reinterpret_cast<h8*>(&sWB[bs * 2048 + wvh + lane * 8]) = tw;
    __syncthreads();
    setup(p + 1, nxt.r0, nxt.r1, nxt.r2, nxt);
    consume(cur, bc);
  };

  GS A, B;
  // prologue: stage wB(0) into buf0; raws 0,1; gathers for pass 0
  {
    h8 tw = *reinterpret_cast<const h8*>(wBc + wvb + lane16);
    float t0, t1, t2;
    rawloadv(t0, t1, t2);                        // p = 0
    rawloadv(B.r0, B.r1, B.r2);                  // p = 1
    *reinterpret_cast<h8*>(&sWB[wvh + lane * 8]) = tw;
    setup(0, t0, t1, t2, A);
  }

  int bc = 0;
#pragma unroll 1
  for (int it = 0; it < 8; ++it) {     // bodies p = 0..15 (full pipeline)
    body(2 * it, bc, A, B);
    bc = (bc == 2) ? 0 : bc + 1;
    body(2 * it + 1, bc, B, A);
    bc = (bc == 2) ? 0 : bc + 1;
  }
  // tail: stage(17)->buf2; barrier; consume(16,buf1); consume(17,buf2)
  {
    h8 tw = *reinterpret_cast<const h8*>(
        wBc + (size_t)17 * 4096 + wvb + lane16);
    setup(17, B.r0, B.r1, B.r2, B);
    *reinterpret_cast<h8*>(&sWB[2 * 2048 + wvh + lane * 8]) = tw;
    __syncthreads();
    consume(A, 1);
    consume(B, 2);
  }

  // epilogue: D[pixel = tq*4+r][cout = f*16+m] -> 128-ch padded-HWC + bias
  const size_t rb = ((size_t)(row + 1) * PW + xw + 1) * 128 + zoff;
#pragma unroll
  for (int f = 0; f < 4; ++f) {
    const int ch = f * 16 + m;
    const float bv = bias[ch];
#pragma unroll
    for (int r = 0; r < 4; ++r)
      actF[rb + (size_t)(tq * 4 + r) * 128 + ch] = (_Float16)(acc[f][r] + bv);
  }
}

// ---------------------------------------------------------------------------
extern "C" void kernel_launch(void* const* d_in, const int* in_sizes, int n_in,
                              void* d_out, int out_size, void* d_ws, size_t ws_size,
                              hipStream_t stream)
{
  const float* feat[2]  = {(const float*)d_in[0], (const float*)d_in[1]};
  const float* extra[2] = {(const float*)d_in[2], (const float*)d_in[3]};
  const float* flow[2]  = {(const float*)d_in[4], (const float*)d_in[5]};
  const float* ow[2][4];
  const float* ob[2][4];
  for (int br = 0; br < 2; ++br)
    for (int j = 0; j < 4; ++j) {
      ow[br][j] = (const float*)d_in[6 + br * 8 + j * 2];
      ob[br][j] = (const float*)d_in[6 + br * 8 + j * 2 + 1];
    }
  const float* dcnw[2] = {(const float*)d_in[22], (const float*)d_in[24]};
  const float* dcnb[2] = {(const float*)d_in[23], (const float*)d_in[25]};
  const float* fusw = (const float*)d_in[26];
  const float* fusb = (const float*)d_in[27];

  char* wsb = (char*)d_ws;
  size_t off = 0;
  auto alloc = [&](size_t bytes) {
    void* p = wsb + off;
    off += (bytes + 255) & ~(size_t)255;
    return p;
  };
  // R1 (34.1 MB), liveness-aliased: actI0/1 (conv0 input) -> actB0/1
  // (conv1 out / conv2 in) -> actF 128-ch (mdcn out / fusion in).
  _Float16* R1 = (_Float16*)alloc(PREC * 128 * 2 * 2);
  _Float16* actI0 = R1;
  _Float16* actI1 = R1 + PREC * 128;
  _Float16* actB0 = R1;
  _Float16* actB1 = R1 + PREC * 64;
  _Float16* actF  = R1;                 // 128-ch padded-HWC
  // R2: actA0/1; after conv3, featG0/1 alias the same space.
  _Float16* R2 = (_Float16*)alloc(PREC * 64 * 2 * 2);
  _Float16* actA0 = R2;
  _Float16* actA1 = R2 + PREC * 64;
  _Float16* featG0 = R2;
  _Float16* featG1 = R2 + PREC * 64;
  _Float16* o2160 = (_Float16*)alloc((size_t)216 * NPIX * 2 * 2);
  _Float16* o2161 = o2160 + (size_t)216 * NPIX;
  _Float16* wB0 = (_Float16*)alloc(73728 * 2);
  _Float16* wB1 = wB0 + 36864;
  _Float16* wb0h[2] = {(_Float16*)alloc(147456), (_Float16*)alloc(147456)};
  _Float16* wb0l[2] = {(_Float16*)alloc(147456), (_Float16*)alloc(147456)};
  _Float16* wb1h[2] = {(_Float16*)alloc(73728), (_Float16*)alloc(73728)};
  _Float16* wb1l[2] = {(_Float16*)alloc(73728), (_Float16*)alloc(73728)};
  _Float16* wb2h[2] = {(_Float16*)alloc(73728), (_Float16*)alloc(73728)};
  _Float16* wb2l[2] = {(_Float16*)alloc(73728), (_Float16*)alloc(73728)};
  _Float16* wb3h[2] = {(_Float16*)alloc(294912), (_Float16*)alloc(294912)};
  _Float16* wb3l[2] = {(_Float16*)alloc(294912), (_Float16*)alloc(294912)};
  _Float16* wbFh = (_Float16*)alloc(147456);   // full 128-cin fusion weights
  float* outp = (float*)d_out;

  dim3 blk256(256);
  zeropad_k<64><<<dim3(33), blk256, 0, stream>>>(actA0);
  zeropad_k<64><<<dim3(33), blk256, 0, stream>>>(actA1);

  // weight prep (both branches; br0 also preps full fusion weights)
  wprep_all_k<<<dim3(198), blk256, 0, stream>>>(
      ow[0][0], ow[0][1], ow[0][2], ow[0][3], fusw, dcnw[0],
      wb0h[0], wb0l[0], wb1h[0], wb1l[0], wb2h[0], wb2l[0],
      wb3h[0], wb3l[0], wbFh, wB0);
  wprep_all_k<<<dim3(162), blk256, 0, stream>>>(
      ow[1][0], ow[1][1], ow[1][2], ow[1][3], nullptr, dcnw[1],
      wb0h[1], wb0l[1], wb1h[1], wb1l[1], wb2h[1], wb2l[1],
      wb3h[1], wb3l[1], nullptr, wB1);

  // activations prep, both branches fused
  prep_hwc_k<128><<<dim3(321, 1, 2), blk256, 0, stream>>>(
      extra[0], extra[1], actI0, actI1);

  // offset network, branch-fused (f16 MFMA, hi/lo-split weights)
  conv_mfma_k<128, 0, true, _Float16><<<dim3(1024, 1, 2), blk256, 0, stream>>>(
      actI0, actI1, wb0h[0], wb0h[1], wb0l[0], wb0l[1],
      ob[0][0], ob[1][0], actA0, actA1, 64, 4);
  zeropad_k<64><<<dim3(33), blk256, 0, stream>>>(actB0);  // actI dead
  zeropad_k<64><<<dim3(33), blk256, 0, stream>>>(actB1);
  conv_mfma_k<64, 0, true, _Float16><<<dim3(1024, 1, 2), blk256, 0, stream>>>(
      actA0, actA1, wb1h[0], wb1h[1], wb1l[0], wb1l[1],
      ob[0][1], ob[1][1], actB0, actB1, 64, 4);
  conv_mfma_k<64, 0, true, _Float16><<<dim3(1024, 1, 2), blk256, 0, stream>>>(
      actB0, actB1, wb2h[0], wb2h[1], wb2l[0], wb2l[1],
      ob[0][2], ob[1][2], actA0, actA1, 64, 4);
  zeropad_k<128><<<dim3(65), blk256, 0, stream>>>(actF);  // actB dead
  conv_mfma_k<64, 1, true, _Float16><<<dim3(1024, 4, 2), blk256, 0, stream>>>(
      actA0, actA1, wb3h[0], wb3h[1], wb3l[0], wb3l[1],
      ob[0][3], ob[1][3], o2160, o2161, 216, 16);

  // deformable conv: featG aliases actA (dead after conv3)
  featg_k<<<dim3(256, 1, 2), blk256, 0, stream>>>(
      feat[0], feat[1], featG0, featG1);
  mdcn_mfma_k<<<dim3(1024, 1, 2), blk256, 0, stream>>>(
      featG0, featG1, o2160, o2161, flow[0], flow[1],
      wB0, wB1, dcnb[0], dcnb[1], actF);

  // single fusion conv over the 128-ch actF
  conv_mfma_k<128, 1, false, float><<<dim3(1024, 1, 1), blk256, 0, stream>>>(
      actF, actF, wbFh, wbFh, nullptr, nullptr,
      fusb, fusb, outp, outp, 64, 4);
}